// Round 5
// baseline (225.162 us; speedup 1.0000x reference)
//
#include <hip/hip_runtime.h>

#define BB     64
#define TT     512
#define EE     128
#define NROWS  (BB * TT)     // 32768
#define PADIDX 1
#define OUTN   1000

typedef __attribute__((ext_vector_type(8)))  short short8;
typedef __attribute__((ext_vector_type(16))) float f32x16;

__device__ __forceinline__ float tanh_fast(float v) {
    return 1.0f - 2.0f / (__expf(2.0f * v) + 1.0f);
}

// split f into bf16 hi (RNE) + bf16 lo (truncated residual): err <= 2^-17 |f|
__device__ __forceinline__ void split8(float4 a0, float4 a1, short8& hi, short8& lo) {
    float f[8] = {a0.x, a0.y, a0.z, a0.w, a1.x, a1.y, a1.z, a1.w};
#pragma unroll
    for (int i = 0; i < 8; ++i) {
        unsigned u = __float_as_uint(f[i]);
        unsigned r = (u + (0x7fffu + ((u >> 16) & 1u))) & 0xffff0000u;
        hi[i] = (short)(r >> 16);
        lo[i] = (short)(__float_as_uint(f[i] - __uint_as_float(r)) >> 16);
    }
}

// ---------------------------------------------------------------------------
// k_prep: W[128][384] fp32 -> bf16 hi/lo B-FRAGMENT images, exact lane order.
// Image index id = ((et*24 + ks)*64 + lane)*8 + j  holds W[e][k] where
//   e = et*32 + (lane&31),  k = ks*16 + (lane>>5)*8 + j.
// A wave's B-frag for (e-tile et, k-step ks) is then 16 contiguous B per lane.
// ---------------------------------------------------------------------------
__global__ __launch_bounds__(256)
void k_prep(const float* __restrict__ W, unsigned short* __restrict__ Whg,
            unsigned short* __restrict__ Wlg)
{
    const int id = blockIdx.x * 256 + threadIdx.x;   // exactly 49152
    const int j  = id & 7;
    const int l  = (id >> 3) & 63;
    const int r2 = id >> 9;            // 0..95
    const int ks = r2 % 24;
    const int et = r2 / 24;
    const int e  = et * 32 + (l & 31);
    const int k  = ks * 16 + (l >> 5) * 8 + j;

    const float v = W[e * 384 + k];
    unsigned u = __float_as_uint(v);
    unsigned r = (u + (0x7fffu + ((u >> 16) & 1u))) & 0xffff0000u;
    Whg[id] = (unsigned short)(r >> 16);
    Wlg[id] = (unsigned short)(__float_as_uint(v - __uint_as_float(r)) >> 16);
}

// ---------------------------------------------------------------------------
// Kernel 1: x = tanh(C @ W^T), s = x . a   — barrier-free register dataflow.
// Grid 512 (BM=64, 2 blocks/CU), 256 thr = 4 waves; wave w owns cols
// [w*32, w*32+32), all 64 rows (mi=0,1). Per k-step: A-frags gathered
// per-lane straight from embeddings (fp32, split to bf16 hi/lo in regs),
// B-frags from the pre-built fragment image (L2-hot). 3-product MFMA.
// ---------------------------------------------------------------------------
__global__ __launch_bounds__(256, 2)
void k_gemm_x(const int* __restrict__ starts, const int* __restrict__ paths,
              const int* __restrict__ ends,
              const float* __restrict__ node_emb, const float* __restrict__ path_emb,
              const unsigned short* __restrict__ Whg, const unsigned short* __restrict__ Wlg,
              const float* __restrict__ a, float* __restrict__ x, float* __restrict__ s)
{
    __shared__ float s_red[64][4];

    const int tid  = threadIdx.x;
    const int lane = tid & 63;
    const int w    = tid >> 6;          // wave id = e-tile (0..3)
    const int fr   = lane & 31;         // frag row (A) / col (B)
    const int kh   = lane >> 5;         // k-half
    const int r0   = blockIdx.x * 64;

    // per-lane A row bases for mi=0/1 x seg=0/1/2 (+kh byte offset baked in)
    const char* base[2][3];
    bool padf[2][3];
#pragma unroll
    for (int mi = 0; mi < 2; ++mi) {
        const int row = r0 + mi * 32 + fr;
        const int i0 = starts[row], i1 = paths[row], i2 = ends[row];
        base[mi][0] = (const char*)node_emb + (size_t)i0 * 512 + kh * 32;
        base[mi][1] = (const char*)path_emb + (size_t)i1 * 512 + kh * 32;
        base[mi][2] = (const char*)node_emb + (size_t)i2 * 512 + kh * 32;
        padf[mi][0] = (i0 == PADIDX);
        padf[mi][1] = false;
        padf[mi][2] = (i2 == PADIDX);
    }

    const char* wbh = (const char*)Whg + ((size_t)(w * 24 * 64) + lane) * 16;
    const char* wbl = (const char*)Wlg + ((size_t)(w * 24 * 64) + lane) * 16;

    f32x16 acc[2];
#pragma unroll
    for (int mi = 0; mi < 2; ++mi)
#pragma unroll
        for (int i = 0; i < 16; ++i) acc[mi][i] = 0.0f;

#pragma unroll
    for (int ks = 0; ks < 24; ++ks) {
        const int seg = ks >> 3;            // compile-time (full unroll)
        const int off = (ks & 7) * 64;

        const short8 bh = *(const short8*)(wbh + ks * 1024);
        const short8 bl = *(const short8*)(wbl + ks * 1024);

        float4 a0[2], a1[2];
#pragma unroll
        for (int mi = 0; mi < 2; ++mi) {
            a0[mi] = *(const float4*)(base[mi][seg] + off);
            a1[mi] = *(const float4*)(base[mi][seg] + off + 16);
            if (padf[mi][seg]) {
                a0[mi] = make_float4(0.f, 0.f, 0.f, 0.f);
                a1[mi] = a0[mi];
            }
        }
#pragma unroll
        for (int mi = 0; mi < 2; ++mi) {
            short8 ah, al;
            split8(a0[mi], a1[mi], ah, al);
            acc[mi] = __builtin_amdgcn_mfma_f32_32x32x16_bf16(ah, bh, acc[mi], 0, 0, 0);
            acc[mi] = __builtin_amdgcn_mfma_f32_32x32x16_bf16(ah, bl, acc[mi], 0, 0, 0);
            acc[mi] = __builtin_amdgcn_mfma_f32_32x32x16_bf16(al, bh, acc[mi], 0, 0, 0);
        }
    }

    // ---- epilogue: tanh, store x, s = x.a (HW-validated C/D mapping) ----
    const float av = a[w * 32 + fr];

#pragma unroll
    for (int mi = 0; mi < 2; ++mi) {
        float sp[16];
#pragma unroll
        for (int r = 0; r < 16; ++r) {
            const int rowl = (r & 3) + 8 * (r >> 2) + 4 * kh;
            const float tv = tanh_fast(acc[mi][r]);
            x[(size_t)(r0 + mi * 32 + rowl) * EE + w * 32 + fr] = tv;
            sp[r] = tv * av;
        }
#pragma unroll
        for (int m = 1; m < 32; m <<= 1)
#pragma unroll
            for (int r = 0; r < 16; ++r) sp[r] += __shfl_xor(sp[r], m, 64);
        if (fr == 0) {
#pragma unroll
            for (int r = 0; r < 16; ++r) {
                const int rowl = (r & 3) + 8 * (r >> 2) + 4 * kh;
                s_red[mi * 32 + rowl][w] = sp[r];
            }
        }
    }
    __syncthreads();
    if (tid < 64)
        s[r0 + tid] = s_red[tid][0] + s_red[tid][1] + s_red[tid][2] + s_red[tid][3];
}

// ---------------------------------------------------------------------------
// Kernel 2: per-b softmax over full T, then weighted sum of x over t < len
// (terms t >= len are masked to 0, so skip reading them entirely).
// Grid 256: block = (b, 32-col e-chunk).
// ---------------------------------------------------------------------------
__global__ __launch_bounds__(256)
void k_attn(const float* __restrict__ s, const int* __restrict__ length,
            const float* __restrict__ x, float* __restrict__ v)
{
    __shared__ float sw[TT];
    __shared__ float red[256];

    const int b   = blockIdx.x >> 2;
    const int ec  = blockIdx.x & 3;
    const int tid = threadIdx.x;

    const float s0 = s[b * TT + tid];
    const float s1 = s[b * TT + 256 + tid];

    red[tid] = fmaxf(s0, s1);
    __syncthreads();
    for (int st = 128; st > 0; st >>= 1) {
        if (tid < st) red[tid] = fmaxf(red[tid], red[tid + st]);
        __syncthreads();
    }
    const float mx = red[0];
    __syncthreads();

    const float e0 = __expf(s0 - mx);
    const float e1 = __expf(s1 - mx);
    red[tid] = e0 + e1;
    __syncthreads();
    for (int st = 128; st > 0; st >>= 1) {
        if (tid < st) red[tid] += red[tid + st];
        __syncthreads();
    }
    const float inv = 1.0f / red[0];
    const int   len = length[b];
    __syncthreads();

    sw[tid]       = e0 * inv;
    sw[tid + 256] = e1 * inv;
    __syncthreads();

    const int e  = ec * 32 + (tid & 31);
    const int tp = tid >> 5;            // 0..7
    const float* xb = x + (size_t)b * TT * EE;
    float acc = 0.0f;
    for (int t = tp; t < len; t += 8)   // only t < len contribute
        acc = fmaf(sw[t], xb[(size_t)t * EE + e], acc);

    red[tid] = acc;
    __syncthreads();
    if (tid < 32) {
        float r2 = 0.0f;
#pragma unroll
        for (int k = 0; k < 8; ++k) r2 += red[k * 32 + tid];
        v[b * EE + ec * 32 + tid] = r2;
    }
}

// ---------------------------------------------------------------------------
// Kernel 3: out[b][o] = v[b] . out_W[o] + out_b[o]
// ---------------------------------------------------------------------------
__global__ __launch_bounds__(256)
void k_out(const float* __restrict__ v, const float* __restrict__ out_W,
           const float* __restrict__ out_b, float* __restrict__ out)
{
    const int id = blockIdx.x * 256 + threadIdx.x;   // 0..63999
    const int o  = id >> 6;
    const int bb = id & 63;

    const float4* vr = (const float4*)(v + bb * EE);
    const float4* wr = (const float4*)(out_W + o * EE);
    float acc = 0.0f;
#pragma unroll 8
    for (int qq = 0; qq < 32; ++qq) {
        const float4 a4 = vr[qq];
        const float4 b4 = wr[qq];
        acc = fmaf(a4.x, b4.x, acc);
        acc = fmaf(a4.y, b4.y, acc);
        acc = fmaf(a4.z, b4.z, acc);
        acc = fmaf(a4.w, b4.w, acc);
    }
    out[bb * OUTN + o] = acc + out_b[o];
}

extern "C" void kernel_launch(void* const* d_in, const int* in_sizes, int n_in,
                              void* d_out, int out_size, void* d_ws, size_t ws_size,
                              hipStream_t stream)
{
    const int*   starts   = (const int*)d_in[0];
    const int*   paths    = (const int*)d_in[1];
    const int*   ends     = (const int*)d_in[2];
    const int*   length   = (const int*)d_in[3];
    const float* node_emb = (const float*)d_in[4];
    const float* path_emb = (const float*)d_in[5];
    const float* W        = (const float*)d_in[6];
    const float* a        = (const float*)d_in[7];
    const float* out_W    = (const float*)d_in[8];
    const float* out_b    = (const float*)d_in[9];
    float*       out      = (float*)d_out;

    // ws: x[32768*128] f32 | s[32768] | v[64*128] | Whg[49152] u16 | Wlg[49152]
    float* x = (float*)d_ws;
    float* s = x + (size_t)NROWS * EE;
    float* v = s + NROWS;
    unsigned short* Whg = (unsigned short*)(v + BB * EE);
    unsigned short* Wlg = Whg + 49152;

    k_prep<<<192, 256, 0, stream>>>(W, Whg, Wlg);
    k_gemm_x<<<NROWS / 64, 256, 0, stream>>>(starts, paths, ends,
                                             node_emb, path_emb, Whg, Wlg,
                                             a, x, s);
    k_attn<<<BB * 4, 256, 0, stream>>>(s, length, x, v);
    k_out<<<(BB * OUTN) / 256, 256, 0, stream>>>(v, out_W, out_b, out);
}

// Round 6
// 219.939 us; speedup vs baseline: 1.0237x; 1.0237x over previous
//
#include <hip/hip_runtime.h>

#define BB     64
#define TT     512
#define EE     128
#define NROWS  (BB * TT)     // 32768
#define PADIDX 1
#define OUTN   1000

typedef __attribute__((ext_vector_type(8)))  short short8;
typedef __attribute__((ext_vector_type(16))) float f32x16;

__device__ __forceinline__ float tanh_fast(float v) {
    return 1.0f - 2.0f / (__expf(2.0f * v) + 1.0f);
}

// split f into bf16 hi (RNE) + bf16 lo (truncated residual): err <= 2^-17 |f|
__device__ __forceinline__ void split8(float4 a0, float4 a1, short8& hi, short8& lo) {
    float f[8] = {a0.x, a0.y, a0.z, a0.w, a1.x, a1.y, a1.z, a1.w};
#pragma unroll
    for (int i = 0; i < 8; ++i) {
        unsigned u = __float_as_uint(f[i]);
        unsigned r = (u + (0x7fffu + ((u >> 16) & 1u))) & 0xffff0000u;
        hi[i] = (short)(r >> 16);
        lo[i] = (short)(__float_as_uint(f[i] - __uint_as_float(r)) >> 16);
    }
}

// ---------------------------------------------------------------------------
// k_prep: W[128][384] fp32 -> bf16 hi/lo B-FRAGMENT images, exact lane order.
// Element id = ((et*24 + ks)*64 + lane)*8 + j  holds W[e][k] where
//   e = et*32 + (lane&31),  k = ks*16 + (lane>>5)*8 + j.
// (validated in round 5)
// ---------------------------------------------------------------------------
__global__ __launch_bounds__(256)
void k_prep(const float* __restrict__ W, unsigned short* __restrict__ Whg,
            unsigned short* __restrict__ Wlg)
{
    const int id = blockIdx.x * 256 + threadIdx.x;   // exactly 49152
    const int j  = id & 7;
    const int l  = (id >> 3) & 63;
    const int r2 = id >> 9;            // 0..95
    const int ks = r2 % 24;
    const int et = r2 / 24;
    const int e  = et * 32 + (l & 31);
    const int k  = ks * 16 + (l >> 5) * 8 + j;

    const float v = W[e * 384 + k];
    unsigned u = __float_as_uint(v);
    unsigned r = (u + (0x7fffu + ((u >> 16) & 1u))) & 0xffff0000u;
    Whg[id] = (unsigned short)(r >> 16);
    Wlg[id] = (unsigned short)(__float_as_uint(v - __uint_as_float(r)) >> 16);
}

// ---------------------------------------------------------------------------
// Kernel 1: x = tanh(C @ W^T), s = x . a  — k-split wave dataflow.
// Block 256 thr = 4 waves: (mg = row-group of 32, kg = K-half of 192).
// Each wave: its own 32 rows x 128 cols x 12 k-steps -> zero duplicated
// gather / split work. Grid 512 (BM=64) -> 2 blocks/CU -> 2 waves/SIMD.
// Bounded pipeline: A prefetch depth 2, B depth 2 (slot index = unroll const).
// Partial acc of kg=1 merged into kg=0 via LDS (one barrier total).
// ---------------------------------------------------------------------------
__global__ __launch_bounds__(256, 2)
void k_gemm_x(const int* __restrict__ starts, const int* __restrict__ paths,
              const int* __restrict__ ends,
              const float* __restrict__ node_emb, const float* __restrict__ path_emb,
              const unsigned short* __restrict__ Whg, const unsigned short* __restrict__ Wlg,
              const float* __restrict__ a, float* __restrict__ x, float* __restrict__ s)
{
    __shared__ float mrg[64 * 128];    // 32 KB merge buffer

    const int tid  = threadIdx.x;
    const int lane = tid & 63;
    const int w    = tid >> 6;
    const int mg   = w >> 1;           // row-group
    const int kg   = w & 1;            // k-group
    const int fr   = lane & 31;
    const int kh   = lane >> 5;
    const int r0   = blockIdx.x * 64;

    const int row = r0 + mg * 32 + fr;
    const int i0 = starts[row], i1 = paths[row], i2 = ends[row];
    const char* baseA0 = (const char*)node_emb + (size_t)i0 * 512 + kh * 32;
    const char* baseA1 = (const char*)path_emb + (size_t)i1 * 512 + kh * 32;
    const char* baseA2 = (const char*)node_emb + (size_t)i2 * 512 + kh * 32;
    const bool pad0 = (i0 == PADIDX), pad2 = (i2 == PADIDX);

    const char* pbh = (const char*)Whg + lane * 16;
    const char* pbl = (const char*)Wlg + lane * 16;

    f32x16 acc[4];
#pragma unroll
    for (int ni = 0; ni < 4; ++ni)
#pragma unroll
        for (int i = 0; i < 16; ++i) acc[ni][i] = 0.0f;

    float4 a0b[2], a1b[2];
    short8 bhb[2][4], blb[2][4];

#define ISSUE_A(SLOT, KS) do {                                                  \
    const int seg_ = (KS) >> 3;                                                 \
    const char* p_ = (seg_ == 0 ? baseA0 : (seg_ == 1 ? baseA1 : baseA2))       \
                   + ((KS) & 7) * 64;                                           \
    a0b[SLOT] = *(const float4*)p_;                                             \
    a1b[SLOT] = *(const float4*)(p_ + 16);                                      \
} while (0)

#define ISSUE_B(SLOT, KS) do {                                                  \
    _Pragma("unroll")                                                           \
    for (int ni_ = 0; ni_ < 4; ++ni_) {                                         \
        bhb[SLOT][ni_] = *(const short8*)(pbh + ni_ * 24576 + (KS) * 1024);     \
        blb[SLOT][ni_] = *(const short8*)(pbl + ni_ * 24576 + (KS) * 1024);     \
    }                                                                           \
} while (0)

#define KLOOP(KS0) do {                                                         \
    ISSUE_A(0, (KS0));  ISSUE_A(1, (KS0) + 1);  ISSUE_B(0, (KS0));              \
    _Pragma("unroll")                                                           \
    for (int j = 0; j < 12; ++j) {                                              \
        const int seg_c = ((KS0) + j) >> 3;                                     \
        float4 ca0 = a0b[j & 1], ca1 = a1b[j & 1];                              \
        const bool pad_ = (seg_c == 0) ? pad0 : ((seg_c == 2) ? pad2 : false);  \
        if (pad_) { ca0 = make_float4(0.f, 0.f, 0.f, 0.f); ca1 = ca0; }         \
        if (j + 2 < 12) ISSUE_A(j & 1, (KS0) + j + 2);                          \
        if (j + 1 < 12) ISSUE_B((j + 1) & 1, (KS0) + j + 1);                    \
        short8 ah, al;                                                          \
        split8(ca0, ca1, ah, al);                                               \
        _Pragma("unroll")                                                       \
        for (int ni = 0; ni < 4; ++ni) {                                        \
            acc[ni] = __builtin_amdgcn_mfma_f32_32x32x16_bf16(ah, bhb[j & 1][ni], acc[ni], 0, 0, 0); \
            acc[ni] = __builtin_amdgcn_mfma_f32_32x32x16_bf16(ah, blb[j & 1][ni], acc[ni], 0, 0, 0); \
            acc[ni] = __builtin_amdgcn_mfma_f32_32x32x16_bf16(al, bhb[j & 1][ni], acc[ni], 0, 0, 0); \
        }                                                                       \
    }                                                                           \
} while (0)

    if (kg == 0) KLOOP(0); else KLOOP(12);

#undef ISSUE_A
#undef ISSUE_B
#undef KLOOP

    // ---- merge k-halves through LDS (layout: [idx][mg*64+lane], conflict-free)
    if (kg == 1) {
#pragma unroll
        for (int ni = 0; ni < 4; ++ni)
#pragma unroll
            for (int r = 0; r < 16; ++r)
                mrg[(ni * 16 + r) * 128 + mg * 64 + lane] = acc[ni][r];
    }
    __syncthreads();

    if (kg == 0) {
#pragma unroll
        for (int ni = 0; ni < 4; ++ni)
#pragma unroll
            for (int r = 0; r < 16; ++r)
                acc[ni][r] += mrg[(ni * 16 + r) * 128 + mg * 64 + lane];

        // ---- epilogue: tanh, store x, s = x.a (HW-validated C/D mapping) ----
        float av[4];
#pragma unroll
        for (int ni = 0; ni < 4; ++ni) av[ni] = a[ni * 32 + fr];

        float sp[16];
#pragma unroll
        for (int r = 0; r < 16; ++r) sp[r] = 0.0f;

#pragma unroll
        for (int ni = 0; ni < 4; ++ni)
#pragma unroll
            for (int r = 0; r < 16; ++r) {
                const int rowl = (r & 3) + 8 * (r >> 2) + 4 * kh;
                const float tv = tanh_fast(acc[ni][r]);
                x[(size_t)(r0 + mg * 32 + rowl) * EE + ni * 32 + fr] = tv;
                sp[r] = fmaf(tv, av[ni], sp[r]);
            }

#pragma unroll
        for (int m = 1; m < 32; m <<= 1)
#pragma unroll
            for (int r = 0; r < 16; ++r) sp[r] += __shfl_xor(sp[r], m, 64);

        if (fr == 0) {
#pragma unroll
            for (int r = 0; r < 16; ++r) {
                const int rowl = (r & 3) + 8 * (r >> 2) + 4 * kh;
                s[r0 + mg * 32 + rowl] = sp[r];
            }
        }
    }
}

// ---------------------------------------------------------------------------
// Kernel 2: per-b softmax over full T, weighted sum of x over t < len.
// Grid 256: block = (b, 32-col e-chunk).
// ---------------------------------------------------------------------------
__global__ __launch_bounds__(256)
void k_attn(const float* __restrict__ s, const int* __restrict__ length,
            const float* __restrict__ x, float* __restrict__ v)
{
    __shared__ float sw[TT];
    __shared__ float red[256];

    const int b   = blockIdx.x >> 2;
    const int ec  = blockIdx.x & 3;
    const int tid = threadIdx.x;

    const float s0 = s[b * TT + tid];
    const float s1 = s[b * TT + 256 + tid];

    red[tid] = fmaxf(s0, s1);
    __syncthreads();
    for (int st = 128; st > 0; st >>= 1) {
        if (tid < st) red[tid] = fmaxf(red[tid], red[tid + st]);
        __syncthreads();
    }
    const float mx = red[0];
    __syncthreads();

    const float e0 = __expf(s0 - mx);
    const float e1 = __expf(s1 - mx);
    red[tid] = e0 + e1;
    __syncthreads();
    for (int st = 128; st > 0; st >>= 1) {
        if (tid < st) red[tid] += red[tid + st];
        __syncthreads();
    }
    const float inv = 1.0f / red[0];
    const int   len = length[b];
    __syncthreads();

    sw[tid]       = e0 * inv;
    sw[tid + 256] = e1 * inv;
    __syncthreads();

    const int e  = ec * 32 + (tid & 31);
    const int tp = tid >> 5;            // 0..7
    const float* xb = x + (size_t)b * TT * EE;
    float acc = 0.0f;
    for (int t = tp; t < len; t += 8)   // only t < len contribute
        acc = fmaf(sw[t], xb[(size_t)t * EE + e], acc);

    red[tid] = acc;
    __syncthreads();
    if (tid < 32) {
        float r2 = 0.0f;
#pragma unroll
        for (int k = 0; k < 8; ++k) r2 += red[k * 32 + tid];
        v[b * EE + ec * 32 + tid] = r2;
    }
}

// ---------------------------------------------------------------------------
// Kernel 3: out[b][o] = v[b] . out_W[o] + out_b[o]
// ---------------------------------------------------------------------------
__global__ __launch_bounds__(256)
void k_out(const float* __restrict__ v, const float* __restrict__ out_W,
           const float* __restrict__ out_b, float* __restrict__ out)
{
    const int id = blockIdx.x * 256 + threadIdx.x;   // 0..63999
    const int o  = id >> 6;
    const int bb = id & 63;

    const float4* vr = (const float4*)(v + bb * EE);
    const float4* wr = (const float4*)(out_W + o * EE);
    float acc = 0.0f;
#pragma unroll 8
    for (int qq = 0; qq < 32; ++qq) {
        const float4 a4 = vr[qq];
        const float4 b4 = wr[qq];
        acc = fmaf(a4.x, b4.x, acc);
        acc = fmaf(a4.y, b4.y, acc);
        acc = fmaf(a4.z, b4.z, acc);
        acc = fmaf(a4.w, b4.w, acc);
    }
    out[bb * OUTN + o] = acc + out_b[o];
}

extern "C" void kernel_launch(void* const* d_in, const int* in_sizes, int n_in,
                              void* d_out, int out_size, void* d_ws, size_t ws_size,
                              hipStream_t stream)
{
    const int*   starts   = (const int*)d_in[0];
    const int*   paths    = (const int*)d_in[1];
    const int*   ends     = (const int*)d_in[2];
    const int*   length   = (const int*)d_in[3];
    const float* node_emb = (const float*)d_in[4];
    const float* path_emb = (const float*)d_in[5];
    const float* W        = (const float*)d_in[6];
    const float* a        = (const float*)d_in[7];
    const float* out_W    = (const float*)d_in[8];
    const float* out_b    = (const float*)d_in[9];
    float*       out      = (float*)d_out;

    // ws: x[32768*128] f32 | s[32768] | v[64*128] | Whg[49152] u16 | Wlg[49152]
    float* x = (float*)d_ws;
    float* s = x + (size_t)NROWS * EE;
    float* v = s + NROWS;
    unsigned short* Whg = (unsigned short*)(v + BB * EE);
    unsigned short* Wlg = Whg + 49152;

    k_prep<<<192, 256, 0, stream>>>(W, Whg, Wlg);
    k_gemm_x<<<NROWS / 64, 256, 0, stream>>>(starts, paths, ends,
                                             node_emb, path_emb, Whg, Wlg,
                                             a, x, s);
    k_attn<<<BB * 4, 256, 0, stream>>>(s, length, x, v);
    k_out<<<(BB * OUTN) / 256, 256, 0, stream>>>(v, out_W, out_b, out);
}